// Round 11
// baseline (3465.491 us; speedup 1.0000x reference)
//
#include <hip/hip_runtime.h>
#include <hip/hip_bf16.h>

typedef unsigned short u16;
typedef short short8 __attribute__((ext_vector_type(8)));
typedef u16 u16x8 __attribute__((ext_vector_type(8)));
typedef float f32x4 __attribute__((ext_vector_type(4)));

#define H 1024
#define NB 16
#define SEQ 256
#define NL 4
#define VOCAB 32000
#define G4 4096
#define YSZ ((size_t)SEQ * NB * H)

__device__ __forceinline__ u16 f2bf(float f) {
  __hip_bfloat16 h = __float2bfloat16(f);
  return *reinterpret_cast<u16*>(&h);
}
__device__ __forceinline__ float sigm(float x) { return 1.0f / (1.0f + __expf(-x)); }
__device__ __forceinline__ float tanhfast(float x) { return 2.0f / (1.0f + __expf(-2.0f * x)) - 1.0f; }

__device__ __forceinline__ f32x4 mfma16(short8 a, short8 b, f32x4 c) {
  return __builtin_amdgcn_mfma_f32_16x16x32_bf16(a, b, c, 0, 0, 0);
}

// Device-coherent 16B load: bypass L1/L2, served by the MALL (round-7 proven:
// 3.7 GB of these cost only 236 MB of HBM FETCH — they hit the MALL).
template <int BOFF>
__device__ __forceinline__ short8 ldg_sc(const u16* p) {
  short8 r;
  asm volatile("global_load_dwordx4 %0, %1, off offset:%2 sc0 sc1"
               : "=&v"(r) : "v"(p), "n"(BOFF));
  return r;
}

#define WAITV0                                                 \
  do {                                                         \
    asm volatile("s_waitcnt vmcnt(0)" ::: "memory");           \
    __builtin_amdgcn_sched_barrier(0);                         \
  } while (0)

#define LD8SC(d, p)                                            \
  do {                                                         \
    d[0] = ldg_sc<0 * 64>(p); d[1] = ldg_sc<1 * 64>(p);        \
    d[2] = ldg_sc<2 * 64>(p); d[3] = ldg_sc<3 * 64>(p);        \
    d[4] = ldg_sc<4 * 64>(p); d[5] = ldg_sc<5 * 64>(p);        \
    d[6] = ldg_sc<6 * 64>(p); d[7] = ldg_sc<7 * 64>(p);        \
  } while (0)

// ---------------- small prep kernels ----------------

__global__ void cvt_bf16(const float* __restrict__ in, u16* __restrict__ out, int n8) {
  const int i = blockIdx.x * blockDim.x + threadIdx.x;
  if (i >= n8) return;
  const float4 a = ((const float4*)in)[2 * i];
  const float4 b = ((const float4*)in)[2 * i + 1];
  u16x8 o;
  o[0] = f2bf(a.x); o[1] = f2bf(a.y); o[2] = f2bf(a.z); o[3] = f2bf(a.w);
  o[4] = f2bf(b.x); o[5] = f2bf(b.y); o[6] = f2bf(b.z); o[7] = f2bf(b.w);
  *(u16x8*)(out + (size_t)i * 8) = o;
}

__global__ void bias_sum(const float* __restrict__ a, const float* __restrict__ b,
                         float* __restrict__ o, int n) {
  const int i = blockIdx.x * blockDim.x + threadIdx.x;
  if (i < n) o[i] = a[i] + b[i];
}

__global__ void zero_u32(unsigned* __restrict__ p, int n) {
  const int i = blockIdx.x * blockDim.x + threadIdx.x;
  if (i < n) p[i] = 0u;
}

__global__ void gather_emb(const int* __restrict__ x, const float* __restrict__ emb,
                           u16* __restrict__ Y) {
  const int row = blockIdx.x;
  const int tok = x[row];
  const float4 v = ((const float4*)(emb + (size_t)tok * H))[threadIdx.x];
  ushort4 o;
  o.x = f2bf(v.x); o.y = f2bf(v.y); o.z = f2bf(v.z); o.w = f2bf(v.w);
  *(ushort4*)(Y + (size_t)row * H + threadIdx.x * 4) = o;
}

// Round-7 proven wait: each of 64 lanes polls one WG flag (64 B-spaced lines:
// ONE writer per line -> lines stay MALL-resident; packed flags caused a
// poll-miss storm, FETCH 236 MB -> 1.8 GB in rounds 8/9).
__device__ __forceinline__ void wavewait(const unsigned* __restrict__ base, unsigned tgt) {
  const unsigned* p = base + (threadIdx.x & 63) * 16;
  unsigned v;
  do {
    asm volatile("global_load_dword %0, %1, off sc0 sc1\n\ts_waitcnt vmcnt(0)"
                 : "=&v"(v) : "v"(p) : "memory");
  } while (!__all(v >= tgt));
  __builtin_amdgcn_sched_barrier(0);
}

// ---------------- LSTM: 4-layer wavefront, K-split waves (round-7 EXACT) ----------------
// 256 WGs x 256 thr (1 WG/CU). blockIdx = l*64 + jgrp; WG owns 16 j-columns.
// Wave w owns k-steps [8w, 8w+8) of all 64 slice rows (4 row-tiles).
// Whh: LDS fragment-ordered (conflict-free). Wih: streamed from L1/L2 via
// pointers — off the critical path, and its MFMA block overlaps the h-wait.
// Order per beat (round-7 proven, 1152 us): x-wait -> x loads -> Zx MFMAs ->
// h-wait -> h loads -> Whh MFMAs. (Round-10 h-first reorder: 1325 us. Reverted.)

__global__ __launch_bounds__(256, 1) void lstm_scan(
    const u16* __restrict__ ybase_r, u16* __restrict__ ybase_w,
    const u16* __restrict__ Wih_all, const u16* __restrict__ Whh_all,
    const float* __restrict__ bias_all, const u16* __restrict__ h0_all,
    const float* __restrict__ c0_all, float* __restrict__ hfin_all,
    float* __restrict__ cfin_all, unsigned* __restrict__ bars)
{
  extern __shared__ u16 sm[];  // [0,65536): Whh frags; [65536,73728): reduce; [73728,73984): smh
  u16* __restrict__ smw = sm;
  f32x4* __restrict__ lred = (f32x4*)(sm + 65536);
  u16* __restrict__ smh = sm + 73728;

  const int tid = threadIdx.x;
  const int lane = tid & 63;
  const int wid = tid >> 6;
  const int l = blockIdx.x >> 6;
  const int jgrp = blockIdx.x & 63;
  const int jbase = jgrp * 16;
  const int b = lane & 15;
  const int lg = lane >> 4;
  const int m = lane & 15;
  const int j = jbase + wid * 4 + lg;

  const u16* __restrict__ Yin  = ybase_r + (size_t)l * YSZ;
  u16* __restrict__ Yout       = ybase_w + (size_t)(l + 1) * YSZ;
  const u16* __restrict__ Wih  = Wih_all + (size_t)l * G4 * H;
  const u16* __restrict__ Whh  = Whh_all + (size_t)l * G4 * H;
  const float* __restrict__ bias = bias_all + (size_t)l * G4;
  const u16* __restrict__ h0b  = h0_all + (size_t)l * NB * H;
  const float* __restrict__ c0 = c0_all + (size_t)l * NB * H;
  float* __restrict__ hfin     = hfin_all + (size_t)l * NB * H;
  float* __restrict__ cfin     = cfin_all + (size_t)l * NB * H;
  unsigned* __restrict__ myflags = bars + l * 1024;          // 64 B-spaced flags
  const unsigned* __restrict__ xflags = bars + (l > 0 ? (l - 1) : 0) * 1024;
  unsigned* __restrict__ myflag_wr = myflags + jgrp * 16;

  // ---- stage Whh slice into LDS, fragment-ordered (conflict-free) ----
  // (rt, ks, lane) at u16 offset rt*16384 + ks*512 + lane*8, ks = wid*8+i.
  #pragma unroll
  for (int rt = 0; rt < 4; ++rt) {
    const size_t ar = (size_t)((m & 3) * H + jbase + rt * 4 + (m >> 2));
    const u16* src = Whh + ar * H + lg * 8;
    #pragma unroll
    for (int i = 0; i < 8; ++i) {
      const int ks = wid * 8 + i;
      short8 w = *(const short8*)(src + ks * 32);
      *(short8*)(smw + (size_t)rt * 16384 + (size_t)ks * 512 + lane * 8) = w;
    }
  }
  // Wih row-tile base pointers for this wave's k-quarter (streamed per beat, L1/L2-hot)
  const u16* __restrict__ wr0 = Wih + (size_t)((m & 3) * H + jbase + 0 * 4 + (m >> 2)) * H + (wid * 8) * 32 + lg * 8;
  const u16* __restrict__ wr1 = Wih + (size_t)((m & 3) * H + jbase + 1 * 4 + (m >> 2)) * H + (wid * 8) * 32 + lg * 8;
  const u16* __restrict__ wr2 = Wih + (size_t)((m & 3) * H + jbase + 2 * 4 + (m >> 2)) * H + (wid * 8) * 32 + lg * 8;
  const u16* __restrict__ wr3 = Wih + (size_t)((m & 3) * H + jbase + 3 * 4 + (m >> 2)) * H + (wid * 8) * 32 + lg * 8;
  __syncthreads();

  f32x4 bias4;
  bias4[0] = bias[0 * H + j];
  bias4[1] = bias[1 * H + j];
  bias4[2] = bias[2 * H + j];
  bias4[3] = bias[3 * H + j];

  float c = c0[b * H + j];
  const int boff = b * H + lg * 8;           // per-lane column base within a [16,1024] tile
  const int kboff = wid * 256;               // wave's k-quarter offset (8 ks * 32 u16)
  const u16* __restrict__ smwv = smw + (size_t)wid * 4096 + lane * 8;  // + rt*16384 + i*512

  for (int t = 0; t < SEQ; ++t) {
    // combined wait order (round-7): x first; Zx MFMAs then overlap the h-wait
    const u16* xw = Yin + (size_t)t * (NB * H) + boff + kboff;

    f32x4 a0 = {0.f, 0.f, 0.f, 0.f};
    f32x4 a1 = {0.f, 0.f, 0.f, 0.f};
    f32x4 a2 = {0.f, 0.f, 0.f, 0.f};
    f32x4 a3 = {0.f, 0.f, 0.f, 0.f};

    short8 fx[8];
    if (l == 0) {
      #pragma unroll
      for (int i = 0; i < 8; ++i) fx[i] = *(const short8*)(xw + i * 32);
    } else {
      wavewait(xflags, (unsigned)(t + 1));
      LD8SC(fx, xw);
      WAITV0;
    }
    #pragma unroll
    for (int i = 0; i < 8; ++i) {
      a0 = mfma16(*(const short8*)(wr0 + i * 32), fx[i], a0);
      a1 = mfma16(*(const short8*)(wr1 + i * 32), fx[i], a1);
      a2 = mfma16(*(const short8*)(wr2 + i * 32), fx[i], a2);
      a3 = mfma16(*(const short8*)(wr3 + i * 32), fx[i], a3);
    }

    short8 fh[8];
    if (t == 0) {
      const u16* hw = h0b + boff + kboff;
      #pragma unroll
      for (int i = 0; i < 8; ++i) fh[i] = *(const short8*)(hw + i * 32);
    } else {
      const u16* hw = Yout + (size_t)(t - 1) * (NB * H) + boff + kboff;
      wavewait(myflags, (unsigned)t);
      LD8SC(fh, hw);
      WAITV0;
    }
    #pragma unroll
    for (int i = 0; i < 8; ++i) {
      short8 w0 = *(const short8*)(smwv + 0 * 16384 + i * 512);
      short8 w1 = *(const short8*)(smwv + 1 * 16384 + i * 512);
      short8 w2 = *(const short8*)(smwv + 2 * 16384 + i * 512);
      short8 w3 = *(const short8*)(smwv + 3 * 16384 + i * 512);
      a0 = mfma16(w0, fh[i], a0);
      a1 = mfma16(w1, fh[i], a1);
      a2 = mfma16(w2, fh[i], a2);
      a3 = mfma16(w3, fh[i], a3);
    }

    // ---- cross-wave reduce: wave w keeps row-tile w, ships the rest via LDS ----
    if (wid != 0) lred[(0 * 4 + wid) * 64 + lane] = a0;
    if (wid != 1) lred[(1 * 4 + wid) * 64 + lane] = a1;
    if (wid != 2) lred[(2 * 4 + wid) * 64 + lane] = a2;
    if (wid != 3) lred[(3 * 4 + wid) * 64 + lane] = a3;
    __syncthreads();

    f32x4 z4 = bias4;
    if (wid == 0)      z4 += a0;
    else if (wid == 1) z4 += a1;
    else if (wid == 2) z4 += a2;
    else               z4 += a3;
    #pragma unroll
    for (int w2 = 0; w2 < 4; ++w2)
      if (w2 != wid) z4 += lred[(wid * 4 + w2) * 64 + lane];

    const float ig = sigm(z4[0]);
    const float fg = sigm(z4[1]);
    const float gg = tanhfast(z4[2]);
    const float og = sigm(z4[3]);
    c = fg * c + ig * gg;
    const float h = og * tanhfast(c);

    smh[b * 16 + wid * 4 + lg] = f2bf(h);
    if (t == SEQ - 1) {
      hfin[b * H + j] = h;
      cfin[b * H + j] = c;
    }

    __syncthreads();  // smh complete
    if (wid == 0) {
      if (lane < 32) {
        const int br = lane >> 1, half = lane & 1;
        u16x8 pv = *(const u16x8*)&smh[br * 16 + half * 8];
        const u16* dst = Yout + (size_t)t * (NB * H) + (size_t)br * H + jbase + half * 8;
        asm volatile("global_store_dwordx4 %0, %1, off sc0 sc1"
                     :: "v"(dst), "v"(pv) : "memory");
      }
      asm volatile("s_waitcnt vmcnt(0)" ::: "memory");  // h at coherence point
      if (lane == 0) {
        const unsigned tv = (unsigned)(t + 1);
        asm volatile("global_store_dword %0, %1, off sc0 sc1"
                     :: "v"(myflag_wr), "v"(tv) : "memory");
      }
    }
  }
}

// ---------------- bf16 GEMM C = A @ Bw^T + bias: 128x256 tile, acc[4][8] ----------------
// K=1024 -> only 16 K-tiles; doubling FLOPs per barrier-pair halves the
// per-FLOP staging/barrier overhead that capped the 128x128 version at ~571 TF.
// Same verified fragment mapping and epilogue form as the proven kernel.

__global__ __launch_bounds__(256, 1) void gemm_bt_bias(
    const u16* __restrict__ A, const u16* __restrict__ Bw,
    const float* __restrict__ bias, float* __restrict__ C, int N)
{
  __shared__ u16 As[128 * 64];   // 16 KB
  __shared__ u16 Bs[256 * 64];   // 32 KB
  const int tid = threadIdx.x;
  const int lane = tid & 63;
  const int wid = tid >> 6;
  const int m0 = blockIdx.x * 128;
  const int n0 = blockIdx.y * 256;
  const int wr = wid >> 1;       // M half (64 rows)
  const int wc = wid & 1;        // N half (128 cols)
  const int lr = lane >> 3;
  const int lc = (lane & 7) * 8;
  f32x4 acc[4][8] = {};

  for (int k0 = 0; k0 < H; k0 += 64) {
    __syncthreads();
    #pragma unroll
    for (int cc = 0; cc < 4; ++cc) {
      const int row = wid * 32 + cc * 8 + lr;   // 0..127
      __builtin_amdgcn_global_load_lds(
          (const __attribute__((address_space(1))) void*)(A + (size_t)(m0 + row) * H + k0 + lc),
          (__attribute__((address_space(3))) void*)(As + row * 64 + lc), 16, 0, 0);
    }
    #pragma unroll
    for (int cc = 0; cc < 8; ++cc) {
      const int row = wid * 64 + cc * 8 + lr;   // 0..255
      __builtin_amdgcn_global_load_lds(
          (const __attribute__((address_space(1))) void*)(Bw + (size_t)(n0 + row) * H + k0 + lc),
          (__attribute__((address_space(3))) void*)(Bs + row * 64 + lc), 16, 0, 0);
    }
    __syncthreads();
    #pragma unroll
    for (int ks = 0; ks < 2; ++ks) {
      short8 af[4], bfr[8];
      #pragma unroll
      for (int i = 0; i < 4; ++i)
        af[i]  = *(const short8*)&As[(wr * 64 + i * 16 + (lane & 15)) * 64 + ks * 32 + (lane >> 4) * 8];
      #pragma unroll
      for (int jj = 0; jj < 8; ++jj)
        bfr[jj] = *(const short8*)&Bs[(wc * 128 + jj * 16 + (lane & 15)) * 64 + ks * 32 + (lane >> 4) * 8];
      #pragma unroll
      for (int i = 0; i < 4; ++i) {
        #pragma unroll
        for (int jj = 0; jj < 8; ++jj)
          acc[i][jj] = mfma16(af[i], bfr[jj], acc[i][jj]);
      }
    }
  }

  #pragma unroll
  for (int jj = 0; jj < 8; ++jj) {
    const int col = n0 + wc * 128 + jj * 16 + (lane & 15);
    const float bv = bias[col];
    #pragma unroll
    for (int i = 0; i < 4; ++i) {
      const int rbase = m0 + wr * 64 + i * 16 + (lane >> 4) * 4;
      #pragma unroll
      for (int r = 0; r < 4; ++r)
        C[(size_t)(rbase + r) * N + col] = acc[i][jj][r] + bv;
    }
  }
}

// ---------------- launch ----------------

extern "C" void kernel_launch(void* const* d_in, const int* in_sizes, int n_in,
                              void* d_out, int out_size, void* d_ws, size_t ws_size,
                              hipStream_t stream) {
  const int*   x    = (const int*)d_in[0];
  const float* h0   = (const float*)d_in[1];
  const float* c0   = (const float*)d_in[2];
  const float* emb  = (const float*)d_in[3];
  const float* W_ih = (const float*)d_in[4];
  const float* W_hh = (const float*)d_in[5];
  const float* b_ih = (const float*)d_in[6];
  const float* b_hh = (const float*)d_in[7];
  const float* fc_W = (const float*)d_in[8];
  const float* fc_b = (const float*)d_in[9];
  float* out = (float*)d_out;
  char* ws = (char*)d_ws;

  size_t off = 0;
  u16* WihB = (u16*)(ws + off); off += (size_t)NL * G4 * H * 2;   // 33.6 MB
  u16* WhhB = (u16*)(ws + off); off += (size_t)NL * G4 * H * 2;   // 33.6 MB
  u16* fcWB = (u16*)(ws + off); off += (size_t)VOCAB * H * 2;     // 65.5 MB
  u16* h0B  = (u16*)(ws + off); off += (size_t)NL * NB * H * 2;
  float* biasB = (float*)(ws + off); off += (size_t)NL * G4 * 4;
  u16* ybufs = (u16*)(ws + off); off += (size_t)(NL + 1) * YSZ * 2;  // 41.9 MB
  unsigned* bars = (unsigned*)(ws + off); off += 16384;
  if (ws_size < off) return;  // fail loudly rather than corrupt

  int n8;
  n8 = NL * G4 * H / 8;  cvt_bf16<<<(n8 + 255) / 256, 256, 0, stream>>>(W_ih, WihB, n8);
  n8 = NL * G4 * H / 8;  cvt_bf16<<<(n8 + 255) / 256, 256, 0, stream>>>(W_hh, WhhB, n8);
  n8 = VOCAB * H / 8;    cvt_bf16<<<(n8 + 255) / 256, 256, 0, stream>>>(fc_W, fcWB, n8);
  n8 = NL * NB * H / 8;  cvt_bf16<<<(n8 + 255) / 256, 256, 0, stream>>>(h0, h0B, n8);
  bias_sum<<<(NL * G4 + 255) / 256, 256, 0, stream>>>(b_ih, b_hh, biasB, NL * G4);
  zero_u32<<<16, 256, 0, stream>>>(bars, 4096);
  gather_emb<<<SEQ * NB, 256, 0, stream>>>(x, emb, ybufs);

  float* hfin = out + (size_t)SEQ * NB * VOCAB;
  float* cfin = hfin + (size_t)NL * NB * H;

  lstm_scan<<<NL * 64, 256, 147968, stream>>>(
      ybufs, ybufs, WihB, WhhB, biasB, h0B, c0, hfin, cfin, bars);

  gemm_bt_bias<<<dim3(32, 125), 256, 0, stream>>>(
      ybufs + (size_t)NL * YSZ, fcWB, fc_b, out, VOCAB);
}

// Round 12
// 1954.752 us; speedup vs baseline: 1.7729x; 1.7729x over previous
//
#include <hip/hip_runtime.h>
#include <hip/hip_bf16.h>

typedef unsigned short u16;
typedef short short8 __attribute__((ext_vector_type(8)));
typedef u16 u16x8 __attribute__((ext_vector_type(8)));
typedef float f32x4 __attribute__((ext_vector_type(4)));

#define H 1024
#define NB 16
#define SEQ 256
#define NL 4
#define VOCAB 32000
#define G4 4096
#define YSZ ((size_t)SEQ * NB * H)

__device__ __forceinline__ u16 f2bf(float f) {
  __hip_bfloat16 h = __float2bfloat16(f);
  return *reinterpret_cast<u16*>(&h);
}
__device__ __forceinline__ float sigm(float x) { return 1.0f / (1.0f + __expf(-x)); }
__device__ __forceinline__ float tanhfast(float x) { return 2.0f / (1.0f + __expf(-2.0f * x)) - 1.0f; }

__device__ __forceinline__ f32x4 mfma16(short8 a, short8 b, f32x4 c) {
  return __builtin_amdgcn_mfma_f32_16x16x32_bf16(a, b, c, 0, 0, 0);
}

// Device-coherent 16B load: bypass L1/L2, served by the MALL.
template <int BOFF>
__device__ __forceinline__ short8 ldg_sc(const u16* p) {
  short8 r;
  asm volatile("global_load_dwordx4 %0, %1, off offset:%2 sc0 sc1"
               : "=&v"(r) : "v"(p), "n"(BOFF));
  return r;
}
// Cached 16B load via asm (deterministic vmcnt accounting for counted waits).
template <int BOFF>
__device__ __forceinline__ short8 ldg_ca(const u16* p) {
  short8 r;
  asm volatile("global_load_dwordx4 %0, %1, off offset:%2"
               : "=&v"(r) : "v"(p), "n"(BOFF));
  return r;
}

#define LD8SC(d, p)                                            \
  do {                                                         \
    d[0] = ldg_sc<0 * 64>(p); d[1] = ldg_sc<1 * 64>(p);        \
    d[2] = ldg_sc<2 * 64>(p); d[3] = ldg_sc<3 * 64>(p);        \
    d[4] = ldg_sc<4 * 64>(p); d[5] = ldg_sc<5 * 64>(p);        \
    d[6] = ldg_sc<6 * 64>(p); d[7] = ldg_sc<7 * 64>(p);        \
  } while (0)
#define LD8CA(d, p)                                            \
  do {                                                         \
    d[0] = ldg_ca<0 * 64>(p); d[1] = ldg_ca<1 * 64>(p);        \
    d[2] = ldg_ca<2 * 64>(p); d[3] = ldg_ca<3 * 64>(p);        \
    d[4] = ldg_ca<4 * 64>(p); d[5] = ldg_ca<5 * 64>(p);        \
    d[6] = ldg_ca<6 * 64>(p); d[7] = ldg_ca<7 * 64>(p);        \
  } while (0)

// ---------------- small prep kernels ----------------

__global__ void cvt_bf16(const float* __restrict__ in, u16* __restrict__ out, int n8) {
  const int i = blockIdx.x * blockDim.x + threadIdx.x;
  if (i >= n8) return;
  const float4 a = ((const float4*)in)[2 * i];
  const float4 b = ((const float4*)in)[2 * i + 1];
  u16x8 o;
  o[0] = f2bf(a.x); o[1] = f2bf(a.y); o[2] = f2bf(a.z); o[3] = f2bf(a.w);
  o[4] = f2bf(b.x); o[5] = f2bf(b.y); o[6] = f2bf(b.z); o[7] = f2bf(b.w);
  *(u16x8*)(out + (size_t)i * 8) = o;
}

__global__ void bias_sum(const float* __restrict__ a, const float* __restrict__ b,
                         float* __restrict__ o, int n) {
  const int i = blockIdx.x * blockDim.x + threadIdx.x;
  if (i < n) o[i] = a[i] + b[i];
}

__global__ void zero_u32(unsigned* __restrict__ p, int n) {
  const int i = blockIdx.x * blockDim.x + threadIdx.x;
  if (i < n) p[i] = 0u;
}

__global__ void gather_emb(const int* __restrict__ x, const float* __restrict__ emb,
                           u16* __restrict__ Y) {
  const int row = blockIdx.x;
  const int tok = x[row];
  const float4 v = ((const float4*)(emb + (size_t)tok * H))[threadIdx.x];
  ushort4 o;
  o.x = f2bf(v.x); o.y = f2bf(v.y); o.z = f2bf(v.z); o.w = f2bf(v.w);
  *(ushort4*)(Y + (size_t)row * H + threadIdx.x * 4) = o;
}

// Merged wait over SPACED flag arrays (64 B-spaced lines, one writer per line —
// the proven-safe layout; rounds 8/9's regression was PACKED flags, not merging).
// One loop checks x-flag >= xt AND h-flag >= ht; unsigned compare makes
// target==0 vacuous (l==0 / t==0).
__device__ __forceinline__ void pollboth_sp(const unsigned* __restrict__ xp, unsigned xt,
                                            const unsigned* __restrict__ hp, unsigned ht) {
  unsigned xv, hv;
  do {
    asm volatile("global_load_dword %0, %2, off sc0 sc1\n\t"
                 "global_load_dword %1, %3, off sc0 sc1\n\t"
                 "s_waitcnt vmcnt(0)"
                 : "=&v"(xv), "=&v"(hv) : "v"(xp), "v"(hp) : "memory");
  } while (!__all(xv >= xt && hv >= ht));
  __builtin_amdgcn_sched_barrier(0);
}

// ---------------- LSTM: 4-layer wavefront, K-split waves ----------------
// 256 WGs x 256 thr (1 WG/CU). blockIdx = l*64 + jgrp; WG owns 16 j-columns.
// Wave w owns k-steps [8w, 8w+8) of all 64 slice rows (4 row-tiles).
// Whh: LDS fragment-ordered. Wih: register-resident WI[32] (asm-pinned; lands
// in VGPR+AGPR — round-11 showed streaming it from cache costs 1.4 GB FETCH
// and 2.1x time once real waits synchronize the WGs' load bursts).
// Per beat: merged poll (x & h) -> fx asm loads, fh asm loads -> vmcnt(8):
// Zx MFMAs (regs) overlap fh flight -> vmcnt(0) -> Whh MFMAs (LDS) -> reduce
// -> gates -> publish (sc stores + drain + 64B-spaced flag store).

__global__ __launch_bounds__(256, 1) void lstm_scan(
    const u16* __restrict__ ybase_r, u16* __restrict__ ybase_w,
    const u16* __restrict__ Wih_all, const u16* __restrict__ Whh_all,
    const float* __restrict__ bias_all, const u16* __restrict__ h0_all,
    const float* __restrict__ c0_all, float* __restrict__ hfin_all,
    float* __restrict__ cfin_all, unsigned* __restrict__ bars)
{
  extern __shared__ u16 sm[];  // [0,65536): Whh frags; [65536,73728): reduce; [73728,73984): smh
  u16* __restrict__ smw = sm;
  f32x4* __restrict__ lred = (f32x4*)(sm + 65536);
  u16* __restrict__ smh = sm + 73728;

  const int tid = threadIdx.x;
  const int lane = tid & 63;
  const int wid = tid >> 6;
  const int l = blockIdx.x >> 6;
  const int jgrp = blockIdx.x & 63;
  const int jbase = jgrp * 16;
  const int b = lane & 15;
  const int lg = lane >> 4;
  const int m = lane & 15;
  const int j = jbase + wid * 4 + lg;

  const u16* __restrict__ Yin  = ybase_r + (size_t)l * YSZ;
  u16* __restrict__ Yout       = ybase_w + (size_t)(l + 1) * YSZ;
  const u16* __restrict__ Wih  = Wih_all + (size_t)l * G4 * H;
  const u16* __restrict__ Whh  = Whh_all + (size_t)l * G4 * H;
  const float* __restrict__ bias = bias_all + (size_t)l * G4;
  const u16* __restrict__ h0b  = h0_all + (size_t)l * NB * H;
  const float* __restrict__ c0 = c0_all + (size_t)l * NB * H;
  float* __restrict__ hfin     = hfin_all + (size_t)l * NB * H;
  float* __restrict__ cfin     = cfin_all + (size_t)l * NB * H;
  unsigned* __restrict__ myflags = bars + l * 1024;          // 64 B-spaced flags
  const unsigned* __restrict__ xflags = bars + (l > 0 ? (l - 1) : 0) * 1024;
  unsigned* __restrict__ myflag_wr = myflags + jgrp * 16;
  const unsigned* __restrict__ xfp = xflags + lane * 16;
  const unsigned* __restrict__ hfp = myflags + lane * 16;

  // ---- stage Whh slice into LDS, fragment-ordered (conflict-free) ----
  // (rt, ks, lane) at u16 offset rt*16384 + ks*512 + lane*8, ks = wid*8+i.
  #pragma unroll
  for (int rt = 0; rt < 4; ++rt) {
    const size_t ar = (size_t)((m & 3) * H + jbase + rt * 4 + (m >> 2));
    const u16* src = Whh + ar * H + lg * 8;
    #pragma unroll
    for (int i = 0; i < 8; ++i) {
      const int ks = wid * 8 + i;
      short8 w = *(const short8*)(src + ks * 32);
      *(short8*)(smw + (size_t)rt * 16384 + (size_t)ks * 512 + lane * 8) = w;
    }
  }
  // ---- Wih k-quarter -> registers (asm-pinned; spill side lands in AGPRs) ----
  short8 WI[32];
  #pragma unroll
  for (int rt = 0; rt < 4; ++rt) {
    const size_t ar = (size_t)((m & 3) * H + jbase + rt * 4 + (m >> 2));
    const u16* src = Wih + ar * H + lg * 8;
    #pragma unroll
    for (int i = 0; i < 8; ++i) {
      WI[rt * 8 + i] = *(const short8*)(src + (wid * 8 + i) * 32);
      asm volatile("" : "+v"(WI[rt * 8 + i]));
    }
  }
  __syncthreads();

  f32x4 bias4;
  bias4[0] = bias[0 * H + j];
  bias4[1] = bias[1 * H + j];
  bias4[2] = bias[2 * H + j];
  bias4[3] = bias[3 * H + j];

  float c = c0[b * H + j];
  const int boff = b * H + lg * 8;           // per-lane column base within a [16,1024] tile
  const int kboff = wid * 256;               // wave's k-quarter offset (8 ks * 32 u16)
  const u16* __restrict__ smwv = smw + (size_t)wid * 4096 + lane * 8;  // + rt*16384 + i*512

  for (int t = 0; t < SEQ; ++t) {
    const u16* xw = Yin + (size_t)t * (NB * H) + boff + kboff;
    const u16* hw = (t == 0 ? h0b : Yout + (size_t)(t - 1) * (NB * H)) + boff + kboff;

    const unsigned xt = (l > 0) ? (unsigned)(t + 1) : 0u;
    const unsigned ht = (unsigned)t;
    if ((xt | ht) != 0u) pollboth_sp(xfp, xt, hfp, ht);

    // deterministic issue order: fx (8) then fh (8); all asm loads so the
    // counted vmcnt below is exact.
    short8 fx[8], fh[8];
    if (l > 0) { LD8SC(fx, xw); } else { LD8CA(fx, xw); }
    if (t > 0) { LD8SC(fh, hw); } else { LD8CA(fh, hw); }

    asm volatile("s_waitcnt vmcnt(8)" ::: "memory");   // fx complete
    __builtin_amdgcn_sched_barrier(0);

    f32x4 a0 = {0.f, 0.f, 0.f, 0.f};
    f32x4 a1 = {0.f, 0.f, 0.f, 0.f};
    f32x4 a2 = {0.f, 0.f, 0.f, 0.f};
    f32x4 a3 = {0.f, 0.f, 0.f, 0.f};

    // Zx = Wih @ x_t — pure register MFMAs, overlap fh flight
    #pragma unroll
    for (int i = 0; i < 8; ++i) {
      a0 = mfma16(WI[0 * 8 + i], fx[i], a0);
      a1 = mfma16(WI[1 * 8 + i], fx[i], a1);
      a2 = mfma16(WI[2 * 8 + i], fx[i], a2);
      a3 = mfma16(WI[3 * 8 + i], fx[i], a3);
    }

    __builtin_amdgcn_sched_barrier(0);
    asm volatile("s_waitcnt vmcnt(0)" ::: "memory");   // fh complete
    __builtin_amdgcn_sched_barrier(0);

    // += Whh @ h_{t-1} (A-frags from LDS)
    #pragma unroll
    for (int i = 0; i < 8; ++i) {
      short8 w0 = *(const short8*)(smwv + 0 * 16384 + i * 512);
      short8 w1 = *(const short8*)(smwv + 1 * 16384 + i * 512);
      short8 w2 = *(const short8*)(smwv + 2 * 16384 + i * 512);
      short8 w3 = *(const short8*)(smwv + 3 * 16384 + i * 512);
      a0 = mfma16(w0, fh[i], a0);
      a1 = mfma16(w1, fh[i], a1);
      a2 = mfma16(w2, fh[i], a2);
      a3 = mfma16(w3, fh[i], a3);
    }

    // ---- cross-wave reduce: wave w keeps row-tile w, ships the rest via LDS ----
    if (wid != 0) lred[(0 * 4 + wid) * 64 + lane] = a0;
    if (wid != 1) lred[(1 * 4 + wid) * 64 + lane] = a1;
    if (wid != 2) lred[(2 * 4 + wid) * 64 + lane] = a2;
    if (wid != 3) lred[(3 * 4 + wid) * 64 + lane] = a3;
    __syncthreads();

    f32x4 z4 = bias4;
    if (wid == 0)      z4 += a0;
    else if (wid == 1) z4 += a1;
    else if (wid == 2) z4 += a2;
    else               z4 += a3;
    #pragma unroll
    for (int w2 = 0; w2 < 4; ++w2)
      if (w2 != wid) z4 += lred[(wid * 4 + w2) * 64 + lane];

    const float ig = sigm(z4[0]);
    const float fg = sigm(z4[1]);
    const float gg = tanhfast(z4[2]);
    const float og = sigm(z4[3]);
    c = fg * c + ig * gg;
    const float h = og * tanhfast(c);

    smh[b * 16 + wid * 4 + lg] = f2bf(h);
    if (t == SEQ - 1) {
      hfin[b * H + j] = h;
      cfin[b * H + j] = c;
    }

    __syncthreads();  // smh complete
    if (wid == 0) {
      if (lane < 32) {
        const int br = lane >> 1, half = lane & 1;
        u16x8 pv = *(const u16x8*)&smh[br * 16 + half * 8];
        const u16* dst = Yout + (size_t)t * (NB * H) + (size_t)br * H + jbase + half * 8;
        asm volatile("global_store_dwordx4 %0, %1, off sc0 sc1"
                     :: "v"(dst), "v"(pv) : "memory");
      }
      asm volatile("s_waitcnt vmcnt(0)" ::: "memory");  // h at coherence point
      if (lane == 0) {
        const unsigned tv = (unsigned)(t + 1);
        asm volatile("global_store_dword %0, %1, off sc0 sc1"
                     :: "v"(myflag_wr), "v"(tv) : "memory");
      }
    }
  }
}

// ---------------- bf16 GEMM C = A @ Bw^T + bias (128x128, XCD m-clustered) ----------------
// Remap linear block id so XCD k (= id % 8, round-robin dispatch) owns m-tiles
// [4k, 4k+4) across ALL n: its 1 MB A-slice stays L2-resident, removing ~2 GB
// of A re-fetch from the MALL (the apparent bound at 470 us).

__global__ __launch_bounds__(256, 1) void gemm_bt_bias(
    const u16* __restrict__ A, const u16* __restrict__ Bw,
    const float* __restrict__ bias, float* __restrict__ C, int N)
{
  __shared__ u16 As[128 * 64];
  __shared__ u16 Bs[128 * 64];
  const int tid = threadIdx.x;
  const int lane = tid & 63;
  const int wid = tid >> 6;
  const unsigned id = blockIdx.x + gridDim.x * blockIdx.y;  // 0..7999
  const unsigned xcd = id & 7u, seq = id >> 3;              // seq 0..999
  const int m0 = (int)(xcd * 4 + (seq & 3u)) * 128;         // m-tile 0..31
  const int n0 = (int)(seq >> 2) * 128;                     // n-tile 0..249
  const int wr = wid >> 1, wc = wid & 1;
  const int lr = lane >> 3;
  const int lc = (lane & 7) * 8;
  f32x4 acc[4][4] = {};

  for (int k0 = 0; k0 < H; k0 += 64) {
    __syncthreads();
    #pragma unroll
    for (int cc = 0; cc < 4; ++cc) {
      const int row = wid * 32 + cc * 8 + lr;
      __builtin_amdgcn_global_load_lds(
          (const __attribute__((address_space(1))) void*)(A + (size_t)(m0 + row) * H + k0 + lc),
          (__attribute__((address_space(3))) void*)(As + row * 64 + lc), 16, 0, 0);
      __builtin_amdgcn_global_load_lds(
          (const __attribute__((address_space(1))) void*)(Bw + (size_t)(n0 + row) * H + k0 + lc),
          (__attribute__((address_space(3))) void*)(Bs + row * 64 + lc), 16, 0, 0);
    }
    __syncthreads();
    #pragma unroll
    for (int ks = 0; ks < 2; ++ks) {
      short8 af[4], bfr[4];
      #pragma unroll
      for (int i = 0; i < 4; ++i) {
        af[i]  = *(const short8*)&As[(wr * 64 + i * 16 + (lane & 15)) * 64 + ks * 32 + (lane >> 4) * 8];
        bfr[i] = *(const short8*)&Bs[(wc * 64 + i * 16 + (lane & 15)) * 64 + ks * 32 + (lane >> 4) * 8];
      }
      #pragma unroll
      for (int i = 0; i < 4; ++i) {
        #pragma unroll
        for (int jj = 0; jj < 4; ++jj)
          acc[i][jj] = mfma16(af[i], bfr[jj], acc[i][jj]);
      }
    }
  }

  #pragma unroll
  for (int jj = 0; jj < 4; ++jj) {
    const int col = n0 + wc * 64 + jj * 16 + (lane & 15);
    const float bv = bias[col];
    #pragma unroll
    for (int i = 0; i < 4; ++i) {
      const int rbase = m0 + wr * 64 + i * 16 + (lane >> 4) * 4;
      #pragma unroll
      for (int r = 0; r < 4; ++r)
        C[(size_t)(rbase + r) * N + col] = acc[i][jj][r] + bv;
    }
  }
}

// ---------------- launch ----------------

extern "C" void kernel_launch(void* const* d_in, const int* in_sizes, int n_in,
                              void* d_out, int out_size, void* d_ws, size_t ws_size,
                              hipStream_t stream) {
  const int*   x    = (const int*)d_in[0];
  const float* h0   = (const float*)d_in[1];
  const float* c0   = (const float*)d_in[2];
  const float* emb  = (const float*)d_in[3];
  const float* W_ih = (const float*)d_in[4];
  const float* W_hh = (const float*)d_in[5];
  const float* b_ih = (const float*)d_in[6];
  const float* b_hh = (const float*)d_in[7];
  const float* fc_W = (const float*)d_in[8];
  const float* fc_b = (const float*)d_in[9];
  float* out = (float*)d_out;
  char* ws = (char*)d_ws;

  size_t off = 0;
  u16* WihB = (u16*)(ws + off); off += (size_t)NL * G4 * H * 2;   // 33.6 MB
  u16* WhhB = (u16*)(ws + off); off += (size_t)NL * G4 * H * 2;   // 33.6 MB
  u16* fcWB = (u16*)(ws + off); off += (size_t)VOCAB * H * 2;     // 65.5 MB
  u16* h0B  = (u16*)(ws + off); off += (size_t)NL * NB * H * 2;
  float* biasB = (float*)(ws + off); off += (size_t)NL * G4 * 4;
  u16* ybufs = (u16*)(ws + off); off += (size_t)(NL + 1) * YSZ * 2;  // 41.9 MB
  unsigned* bars = (unsigned*)(ws + off); off += 16384;
  if (ws_size < off) return;  // fail loudly rather than corrupt

  int n8;
  n8 = NL * G4 * H / 8;  cvt_bf16<<<(n8 + 255) / 256, 256, 0, stream>>>(W_ih, WihB, n8);
  n8 = NL * G4 * H / 8;  cvt_bf16<<<(n8 + 255) / 256, 256, 0, stream>>>(W_hh, WhhB, n8);
  n8 = VOCAB * H / 8;    cvt_bf16<<<(n8 + 255) / 256, 256, 0, stream>>>(fc_W, fcWB, n8);
  n8 = NL * NB * H / 8;  cvt_bf16<<<(n8 + 255) / 256, 256, 0, stream>>>(h0, h0B, n8);
  bias_sum<<<(NL * G4 + 255) / 256, 256, 0, stream>>>(b_ih, b_hh, biasB, NL * G4);
  zero_u32<<<16, 256, 0, stream>>>(bars, 4096);   // ALL flags, every launch (honest syncs)
  gather_emb<<<SEQ * NB, 256, 0, stream>>>(x, emb, ybufs);

  float* hfin = out + (size_t)SEQ * NB * VOCAB;
  float* cfin = hfin + (size_t)NL * NB * H;

  lstm_scan<<<NL * 64, 256, 147968, stream>>>(
      ybufs, ybufs, WihB, WhhB, biasB, h0B, c0, hfin, cfin, bars);

  gemm_bt_bias<<<dim3(32, 250), 256, 0, stream>>>(
      ybufs + (size_t)NL * YSZ, fcWB, fc_b, out, VOCAB);
}

// Round 13
// 1664.313 us; speedup vs baseline: 2.0822x; 1.1745x over previous
//
#include <hip/hip_runtime.h>
#include <hip/hip_bf16.h>

typedef unsigned short u16;
typedef short short8 __attribute__((ext_vector_type(8)));
typedef u16 u16x8 __attribute__((ext_vector_type(8)));
typedef float f32x4 __attribute__((ext_vector_type(4)));
typedef unsigned u32x4v __attribute__((ext_vector_type(4)));

#define H 1024
#define NB 16
#define SEQ 256
#define NL 4
#define VOCAB 32000
#define G4 4096
#define YSZ ((size_t)SEQ * NB * H)
#define SENT 0xFFFFFFFFu

__device__ __forceinline__ u16 f2bf(float f) {
  __hip_bfloat16 h = __float2bfloat16(f);
  return *reinterpret_cast<u16*>(&h);
}
__device__ __forceinline__ float sigm(float x) { return 1.0f / (1.0f + __expf(-x)); }
__device__ __forceinline__ float tanhfast(float x) { return 2.0f / (1.0f + __expf(-2.0f * x)) - 1.0f; }

__device__ __forceinline__ f32x4 mfma16(short8 a, short8 b, f32x4 c) {
  return __builtin_amdgcn_mfma_f32_16x16x32_bf16(a, b, c, 0, 0, 0);
}

// Device-coherent 16B load: bypass L1/L2, served by the MALL.
template <int BOFF>
__device__ __forceinline__ short8 ldg_sc(const u16* p) {
  short8 r;
  asm volatile("global_load_dwordx4 %0, %1, off offset:%2 sc0 sc1"
               : "=&v"(r) : "v"(p), "n"(BOFF));
  return r;
}
// Cached 16B load via asm (keeps vmcnt accounting deterministic).
template <int BOFF>
__device__ __forceinline__ short8 ldg_ca(const u16* p) {
  short8 r;
  asm volatile("global_load_dwordx4 %0, %1, off offset:%2"
               : "=&v"(r) : "v"(p), "n"(BOFF));
  return r;
}

#define LD8SC(d, p)                                            \
  do {                                                         \
    d[0] = ldg_sc<0 * 64>(p); d[1] = ldg_sc<1 * 64>(p);        \
    d[2] = ldg_sc<2 * 64>(p); d[3] = ldg_sc<3 * 64>(p);        \
    d[4] = ldg_sc<4 * 64>(p); d[5] = ldg_sc<5 * 64>(p);        \
    d[6] = ldg_sc<6 * 64>(p); d[7] = ldg_sc<7 * 64>(p);        \
  } while (0)
#define LD8CA(d, p)                                            \
  do {                                                         \
    d[0] = ldg_ca<0 * 64>(p); d[1] = ldg_ca<1 * 64>(p);        \
    d[2] = ldg_ca<2 * 64>(p); d[3] = ldg_ca<3 * 64>(p);        \
    d[4] = ldg_ca<4 * 64>(p); d[5] = ldg_ca<5 * 64>(p);        \
    d[6] = ldg_ca<6 * 64>(p); d[7] = ldg_ca<7 * 64>(p);        \
  } while (0)

// max over all 32 dwords of an 8-packet set; == SENT iff ANY dword unwritten.
__device__ __forceinline__ unsigned maxpk(const short8 (&f)[8]) {
  unsigned mx = 0u;
  #pragma unroll
  for (int i = 0; i < 8; ++i) {
    u32x4v d = __builtin_bit_cast(u32x4v, f[i]);
    mx = d[0] > mx ? d[0] : mx;
    mx = d[1] > mx ? d[1] : mx;
    mx = d[2] > mx ? d[2] : mx;
    mx = d[3] > mx ? d[3] : mx;
  }
  return mx;
}

// ---------------- small prep kernels ----------------

__global__ void cvt_bf16(const float* __restrict__ in, u16* __restrict__ out, int n8) {
  const int i = blockIdx.x * blockDim.x + threadIdx.x;
  if (i >= n8) return;
  const float4 a = ((const float4*)in)[2 * i];
  const float4 b = ((const float4*)in)[2 * i + 1];
  u16x8 o;
  o[0] = f2bf(a.x); o[1] = f2bf(a.y); o[2] = f2bf(a.z); o[3] = f2bf(a.w);
  o[4] = f2bf(b.x); o[5] = f2bf(b.y); o[6] = f2bf(b.z); o[7] = f2bf(b.w);
  *(u16x8*)(out + (size_t)i * 8) = o;
}

__global__ void bias_sum(const float* __restrict__ a, const float* __restrict__ b,
                         float* __restrict__ o, int n) {
  const int i = blockIdx.x * blockDim.x + threadIdx.x;
  if (i < n) o[i] = a[i] + b[i];
}

// sentinel refill of the polled Y buffers (every launch: replays must not see
// the previous replay's non-sentinel data).
__global__ void fill_sent(u32x4v* __restrict__ p) {
  const int i = blockIdx.x * blockDim.x + threadIdx.x;
  u32x4v v = {SENT, SENT, SENT, SENT};
  p[i] = v;
}

__global__ void gather_emb(const int* __restrict__ x, const float* __restrict__ emb,
                           u16* __restrict__ Y) {
  const int row = blockIdx.x;
  const int tok = x[row];
  const float4 v = ((const float4*)(emb + (size_t)tok * H))[threadIdx.x];
  ushort4 o;
  o.x = f2bf(v.x); o.y = f2bf(v.y); o.z = f2bf(v.z); o.w = f2bf(v.w);
  *(ushort4*)(Y + (size_t)row * H + threadIdx.x * 4) = o;
}

// ---------------- LSTM: 4-layer wavefront, K-split waves, sentinel-stamped ----------------
// 256 WGs x 256 thr (1 WG/CU). blockIdx = l*64 + jgrp; WG owns 16 j-columns.
// Wave w owns k-steps [8w, 8w+8) of all 64 slice rows (4 row-tiles).
// Whh: LDS fragment-ordered. Wih: register-resident WI[32] (asm-pinned).
// NO flags, NO publish drain: Y buffers are pre-filled with 0xFFFF (bf16 NaN
// pattern f2bf can never produce from finite gates). Producers fire sc stores
// and move on; consumers poll their own data packets (sc loads) until no dword
// reads 0xFFFFFFFF (torn/partial writes leave sentinel dwords -> retry).
// This merges the flag RT + data RT into a single MALL propagation per beat.

__global__ __launch_bounds__(256, 1) void lstm_scan(
    const u16* __restrict__ ybase_r, u16* __restrict__ ybase_w,
    const u16* __restrict__ Wih_all, const u16* __restrict__ Whh_all,
    const float* __restrict__ bias_all, const u16* __restrict__ h0_all,
    const float* __restrict__ c0_all, float* __restrict__ hfin_all,
    float* __restrict__ cfin_all)
{
  extern __shared__ u16 sm[];  // [0,65536): Whh frags; [65536,73728): reduce; [73728,73984): smh
  u16* __restrict__ smw = sm;
  f32x4* __restrict__ lred = (f32x4*)(sm + 65536);
  u16* __restrict__ smh = sm + 73728;

  const int tid = threadIdx.x;
  const int lane = tid & 63;
  const int wid = tid >> 6;
  const int l = blockIdx.x >> 6;
  const int jgrp = blockIdx.x & 63;
  const int jbase = jgrp * 16;
  const int b = lane & 15;
  const int lg = lane >> 4;
  const int m = lane & 15;
  const int j = jbase + wid * 4 + lg;

  const u16* __restrict__ Yin  = ybase_r + (size_t)l * YSZ;
  u16* __restrict__ Yout       = ybase_w + (size_t)(l + 1) * YSZ;
  const u16* __restrict__ Wih  = Wih_all + (size_t)l * G4 * H;
  const u16* __restrict__ Whh  = Whh_all + (size_t)l * G4 * H;
  const float* __restrict__ bias = bias_all + (size_t)l * G4;
  const u16* __restrict__ h0b  = h0_all + (size_t)l * NB * H;
  const float* __restrict__ c0 = c0_all + (size_t)l * NB * H;
  float* __restrict__ hfin     = hfin_all + (size_t)l * NB * H;
  float* __restrict__ cfin     = cfin_all + (size_t)l * NB * H;

  // ---- stage Whh slice into LDS, fragment-ordered (conflict-free) ----
  // (rt, ks, lane) at u16 offset rt*16384 + ks*512 + lane*8, ks = wid*8+i.
  #pragma unroll
  for (int rt = 0; rt < 4; ++rt) {
    const size_t ar = (size_t)((m & 3) * H + jbase + rt * 4 + (m >> 2));
    const u16* src = Whh + ar * H + lg * 8;
    #pragma unroll
    for (int i = 0; i < 8; ++i) {
      const int ks = wid * 8 + i;
      short8 w = *(const short8*)(src + ks * 32);
      *(short8*)(smw + (size_t)rt * 16384 + (size_t)ks * 512 + lane * 8) = w;
    }
  }
  // ---- Wih k-quarter -> registers (asm-pinned; round-11 proved streaming
  // it from cache costs 1.4 GB FETCH and 2.1x once waits are honest) ----
  short8 WI[32];
  #pragma unroll
  for (int rt = 0; rt < 4; ++rt) {
    const size_t ar = (size_t)((m & 3) * H + jbase + rt * 4 + (m >> 2));
    const u16* src = Wih + ar * H + lg * 8;
    #pragma unroll
    for (int i = 0; i < 8; ++i) {
      WI[rt * 8 + i] = *(const short8*)(src + (wid * 8 + i) * 32);
      asm volatile("" : "+v"(WI[rt * 8 + i]));
    }
  }
  __syncthreads();

  f32x4 bias4;
  bias4[0] = bias[0 * H + j];
  bias4[1] = bias[1 * H + j];
  bias4[2] = bias[2 * H + j];
  bias4[3] = bias[3 * H + j];

  float c = c0[b * H + j];
  const int boff = b * H + lg * 8;           // per-lane column base within a [16,1024] tile
  const int kboff = wid * 256;               // wave's k-quarter offset (8 ks * 32 u16)
  const u16* __restrict__ smwv = smw + (size_t)wid * 4096 + lane * 8;  // + rt*16384 + i*512

  for (int t = 0; t < SEQ; ++t) {
    const u16* xw = Yin + (size_t)t * (NB * H) + boff + kboff;
    const u16* hw = (t == 0 ? h0b : Yout + (size_t)(t - 1) * (NB * H)) + boff + kboff;

    short8 fx[8], fh[8];
    const bool needx = (l > 0);
    const bool needh = (t > 0);
    if (!needx) LD8CA(fx, xw);   // gather_emb output: ready before launch
    if (!needh) LD8CA(fh, hw);   // h0: dispatch input

    if (needx || needh) {
      // sentinel poll: reload waited sets until no dword is 0xFFFFFFFF
      unsigned ok;
      do {
        if (needx) LD8SC(fx, xw);
        if (needh) LD8SC(fh, hw);
        asm volatile("s_waitcnt vmcnt(0)" ::: "memory");
        unsigned mx = 0u;
        if (needx) { unsigned a = maxpk(fx); mx = a > mx ? a : mx; }
        if (needh) { unsigned a = maxpk(fh); mx = a > mx ? a : mx; }
        ok = (mx != SENT);
      } while (!__all(ok));
      __builtin_amdgcn_sched_barrier(0);
    } else {
      asm volatile("s_waitcnt vmcnt(0)" ::: "memory");
      __builtin_amdgcn_sched_barrier(0);
    }

    f32x4 a0 = {0.f, 0.f, 0.f, 0.f};
    f32x4 a1 = {0.f, 0.f, 0.f, 0.f};
    f32x4 a2 = {0.f, 0.f, 0.f, 0.f};
    f32x4 a3 = {0.f, 0.f, 0.f, 0.f};

    // Zx = Wih @ x_t (register A-frags)
    #pragma unroll
    for (int i = 0; i < 8; ++i) {
      a0 = mfma16(WI[0 * 8 + i], fx[i], a0);
      a1 = mfma16(WI[1 * 8 + i], fx[i], a1);
      a2 = mfma16(WI[2 * 8 + i], fx[i], a2);
      a3 = mfma16(WI[3 * 8 + i], fx[i], a3);
    }
    // += Whh @ h_{t-1} (A-frags from LDS)
    #pragma unroll
    for (int i = 0; i < 8; ++i) {
      short8 w0 = *(const short8*)(smwv + 0 * 16384 + i * 512);
      short8 w1 = *(const short8*)(smwv + 1 * 16384 + i * 512);
      short8 w2 = *(const short8*)(smwv + 2 * 16384 + i * 512);
      short8 w3 = *(const short8*)(smwv + 3 * 16384 + i * 512);
      a0 = mfma16(w0, fh[i], a0);
      a1 = mfma16(w1, fh[i], a1);
      a2 = mfma16(w2, fh[i], a2);
      a3 = mfma16(w3, fh[i], a3);
    }

    // ---- cross-wave reduce: wave w keeps row-tile w, ships the rest via LDS ----
    if (wid != 0) lred[(0 * 4 + wid) * 64 + lane] = a0;
    if (wid != 1) lred[(1 * 4 + wid) * 64 + lane] = a1;
    if (wid != 2) lred[(2 * 4 + wid) * 64 + lane] = a2;
    if (wid != 3) lred[(3 * 4 + wid) * 64 + lane] = a3;
    __syncthreads();

    f32x4 z4 = bias4;
    if (wid == 0)      z4 += a0;
    else if (wid == 1) z4 += a1;
    else if (wid == 2) z4 += a2;
    else               z4 += a3;
    #pragma unroll
    for (int w2 = 0; w2 < 4; ++w2)
      if (w2 != wid) z4 += lred[(wid * 4 + w2) * 64 + lane];

    const float ig = sigm(z4[0]);
    const float fg = sigm(z4[1]);
    const float gg = tanhfast(z4[2]);
    const float og = sigm(z4[3]);
    c = fg * c + ig * gg;
    const float h = og * tanhfast(c);

    smh[b * 16 + wid * 4 + lg] = f2bf(h);
    if (t == SEQ - 1) {
      hfin[b * H + j] = h;
      cfin[b * H + j] = c;
    }

    __syncthreads();  // smh complete
    // publish: fire-and-forget sc stores (no drain, no flag — data IS the flag)
    if (wid == 0 && lane < 32) {
      const int br = lane >> 1, half = lane & 1;
      u16x8 pv = *(const u16x8*)&smh[br * 16 + half * 8];
      const u16* dst = Yout + (size_t)t * (NB * H) + (size_t)br * H + jbase + half * 8;
      asm volatile("global_store_dwordx4 %0, %1, off sc0 sc1"
                   :: "v"(dst), "v"(pv) : "memory");
    }
  }
}

// ---------------- bf16 GEMM C = A @ Bw^T + bias (128x128, XCD m-clustered) ----------------

__global__ __launch_bounds__(256, 1) void gemm_bt_bias(
    const u16* __restrict__ A, const u16* __restrict__ Bw,
    const float* __restrict__ bias, float* __restrict__ C, int N)
{
  __shared__ u16 As[128 * 64];
  __shared__ u16 Bs[128 * 64];
  const int tid = threadIdx.x;
  const int lane = tid & 63;
  const int wid = tid >> 6;
  const unsigned id = blockIdx.x + gridDim.x * blockIdx.y;  // 0..7999
  const unsigned xcd = id & 7u, seq = id >> 3;              // seq 0..999
  const int m0 = (int)(xcd * 4 + (seq & 3u)) * 128;         // m-tile 0..31
  const int n0 = (int)(seq >> 2) * 128;                     // n-tile 0..249
  const int wr = wid >> 1, wc = wid & 1;
  const int lr = lane >> 3;
  const int lc = (lane & 7) * 8;
  f32x4 acc[4][4] = {};

  for (int k0 = 0; k0 < H; k0 += 64) {
    __syncthreads();
    #pragma unroll
    for (int cc = 0; cc < 4; ++cc) {
      const int row = wid * 32 + cc * 8 + lr;
      __builtin_amdgcn_global_load_lds(
          (const __attribute__((address_space(1))) void*)(A + (size_t)(m0 + row) * H + k0 + lc),
          (__attribute__((address_space(3))) void*)(As + row * 64 + lc), 16, 0, 0);
      __builtin_amdgcn_global_load_lds(
          (const __attribute__((address_space(1))) void*)(Bw + (size_t)(n0 + row) * H + k0 + lc),
          (__attribute__((address_space(3))) void*)(Bs + row * 64 + lc), 16, 0, 0);
    }
    __syncthreads();
    #pragma unroll
    for (int ks = 0; ks < 2; ++ks) {
      short8 af[4], bfr[4];
      #pragma unroll
      for (int i = 0; i < 4; ++i) {
        af[i]  = *(const short8*)&As[(wr * 64 + i * 16 + (lane & 15)) * 64 + ks * 32 + (lane >> 4) * 8];
        bfr[i] = *(const short8*)&Bs[(wc * 64 + i * 16 + (lane & 15)) * 64 + ks * 32 + (lane >> 4) * 8];
      }
      #pragma unroll
      for (int i = 0; i < 4; ++i) {
        #pragma unroll
        for (int jj = 0; jj < 4; ++jj)
          acc[i][jj] = mfma16(af[i], bfr[jj], acc[i][jj]);
      }
    }
  }

  #pragma unroll
  for (int jj = 0; jj < 4; ++jj) {
    const int col = n0 + wc * 64 + jj * 16 + (lane & 15);
    const float bv = bias[col];
    #pragma unroll
    for (int i = 0; i < 4; ++i) {
      const int rbase = m0 + wr * 64 + i * 16 + (lane >> 4) * 4;
      #pragma unroll
      for (int r = 0; r < 4; ++r)
        C[(size_t)(rbase + r) * N + col] = acc[i][jj][r] + bv;
    }
  }
}

// ---------------- launch ----------------

extern "C" void kernel_launch(void* const* d_in, const int* in_sizes, int n_in,
                              void* d_out, int out_size, void* d_ws, size_t ws_size,
                              hipStream_t stream) {
  const int*   x    = (const int*)d_in[0];
  const float* h0   = (const float*)d_in[1];
  const float* c0   = (const float*)d_in[2];
  const float* emb  = (const float*)d_in[3];
  const float* W_ih = (const float*)d_in[4];
  const float* W_hh = (const float*)d_in[5];
  const float* b_ih = (const float*)d_in[6];
  const float* b_hh = (const float*)d_in[7];
  const float* fc_W = (const float*)d_in[8];
  const float* fc_b = (const float*)d_in[9];
  float* out = (float*)d_out;
  char* ws = (char*)d_ws;

  size_t off = 0;
  u16* WihB = (u16*)(ws + off); off += (size_t)NL * G4 * H * 2;   // 33.6 MB
  u16* WhhB = (u16*)(ws + off); off += (size_t)NL * G4 * H * 2;   // 33.6 MB
  u16* fcWB = (u16*)(ws + off); off += (size_t)VOCAB * H * 2;     // 65.5 MB
  u16* h0B  = (u16*)(ws + off); off += (size_t)NL * NB * H * 2;
  float* biasB = (float*)(ws + off); off += (size_t)NL * G4 * 4;
  u16* ybufs = (u16*)(ws + off); off += (size_t)(NL + 1) * YSZ * 2;  // 41.9 MB
  if (ws_size < off) return;  // fail loudly rather than corrupt

  int n8;
  n8 = NL * G4 * H / 8;  cvt_bf16<<<(n8 + 255) / 256, 256, 0, stream>>>(W_ih, WihB, n8);
  n8 = NL * G4 * H / 8;  cvt_bf16<<<(n8 + 255) / 256, 256, 0, stream>>>(W_hh, WhhB, n8);
  n8 = VOCAB * H / 8;    cvt_bf16<<<(n8 + 255) / 256, 256, 0, stream>>>(fc_W, fcWB, n8);
  n8 = NL * NB * H / 8;  cvt_bf16<<<(n8 + 255) / 256, 256, 0, stream>>>(h0, h0B, n8);
  bias_sum<<<(NL * G4 + 255) / 256, 256, 0, stream>>>(b_ih, b_hh, biasB, NL * G4);
  // sentinel refill of the 4 polled Y buffers (every launch; replay safety):
  // 4 * YSZ u16 = 33.5 MB = 2,097,152 x 16B
  fill_sent<<<8192, 256, 0, stream>>>((u32x4v*)(ybufs + YSZ));
  gather_emb<<<SEQ * NB, 256, 0, stream>>>(x, emb, ybufs);

  float* hfin = out + (size_t)SEQ * NB * VOCAB;
  float* cfin = hfin + (size_t)NL * NB * H;

  lstm_scan<<<NL * 64, 256, 147968, stream>>>(
      ybufs, ybufs, WihB, WhhB, biasB, h0B, c0, hfin, cfin);

  gemm_bt_bias<<<dim3(32, 250), 256, 0, stream>>>(
      ybufs + (size_t)NL * YSZ, fcWB, fc_b, out, VOCAB);
}